// Round 3
// baseline (218.728 us; speedup 1.0000x reference)
//
#include <hip/hip_runtime.h>
#include <cstdint>
#include <cstddef>

// LogMM_19490561589867: x [8,2048,1024] f32, matrix [1024,1024] f32
// out = log(max(x @ matrix, tiny))  [8,2048,1024] f32
// Round-10: single-pass fused GEMM with A-panel resident in LDS.
//  - Each block owns 64 rows for ALL 1024 cols: reads its 256KB f32 A-panel
//    from HBM exactly ONCE, converts to fp8 e4m3 in-register (same RNE cvt
//    -> absmax 0.03125 unchanged), stores 64KB fp8 panel in LDS. Kills both
//    the Ab HBM round-trip (prep write 16MiB + gemm re-read 16MiB) AND
//    round-1's 8x L2 A-amplification (panel read once, period).
//  - B: tiny prep_b transposes/converts matrix -> Bt [N][K] fp8 (1 MiB, ~2us).
//    Main kernel streams 32KB Bt tiles (L2-resident; per-block chunk rotation
//    spreads L2 line pressure) through a double-buffered 2x32KB LDS region:
//    global_load_lds width-16, counted vmcnt(8), raw s_barrier (never drains
//    the prefetch in-loop; T4 pattern).
//  - LDS 128KB total (A 64K @0, B dbuf @64K/@96K) -> 1 block/CU, 256 blocks
//    = exactly 1 per CU. Memory-bound kernel (~136 MiB HBM ~= 21.6us floor);
//    compute floor 7.3us, so 4 waves/CU suffices.
//  - XOR swizzle invariant (proven zero-conflict): 16B chunk c of row r sits
//    at position c^(r&7). A rows are 1024B (== 0 mod 128B -> same bank math).
//  - Epilogue: direct nontemporal dword stores; each instruction covers two
//    full 128B lines (lanes 0-31 row x, lanes 32-63 row x+4) -> WRITE_SIZE
//    ideal, zero barriers, overlaps in-flight B prefetch.
#define M_GLOB 16384
#define N_GLOB 1024
#define K_GLOB 1024

#define BM   64    // block rows (A panel in LDS)
#define BNC  256   // n-chunk cols per accumulation pass
#define NCH  4     // chunks (1024/256)
#define NKT  8     // K tiles of 128 fp8 bytes
#define NT   32    // NCH*NKT pipeline steps

typedef unsigned char  u8;
typedef unsigned short u16;
typedef __attribute__((ext_vector_type(4))) float  f32x4;
typedef __attribute__((ext_vector_type(16))) float f32x16;
typedef __attribute__((ext_vector_type(4))) unsigned int  u32x4;
typedef __attribute__((ext_vector_type(2))) unsigned int  u32x2;
typedef __attribute__((ext_vector_type(8))) int  i32x8;
typedef __attribute__((ext_vector_type(8))) __bf16 bf16x8;

// truncating pack (fallback fused path — round-1 proven numerics)
static __device__ __forceinline__ unsigned pack2_bf16(float lo, float hi) {
    unsigned bl = __builtin_bit_cast(unsigned, lo);
    unsigned bh = __builtin_bit_cast(unsigned, hi);
    return (bh & 0xFFFF0000u) | (bl >> 16);
}

// 4 fp32 -> 4 fp8 e4m3 bytes (HW RNE, OCP on gfx950)
static __device__ __forceinline__ unsigned cvt4_fp8(float a, float b, float c, float d) {
    int w = __builtin_amdgcn_cvt_pk_fp8_f32(a, b, 0, false);
    w = __builtin_amdgcn_cvt_pk_fp8_f32(c, d, w, true);
    return (unsigned)w;
}

// Raw workgroup barrier: compiler memory-clobber but NO vmcnt drain.
static __device__ __forceinline__ void barrier_raw() {
    asm volatile("s_barrier" ::: "memory");
}

// Counted vmcnt wait (literal N): waits until <= N vmem ops outstanding.
// vmcnt retires in order, so vmcnt(8) == "everything older than the 8
// just-issued loads is complete" (m135-verified semantics).
#define VMCNT(n) asm volatile("s_waitcnt vmcnt(" #n ")" ::: "memory")

// Async global->LDS DMA, 16 B per lane (dest = base + lane*16).
static __device__ __forceinline__ void gload_lds16(const u8* g, char* l) {
    __builtin_amdgcn_global_load_lds(
        (const __attribute__((address_space(1))) unsigned int*)g,
        (__attribute__((address_space(3))) unsigned int*)l,
        16, 0, 0);
}

// ---------------------------------------------------------------------------
// B-only prep: Bt_fp8[n][k] = e4m3(B[k][n]), 32x32 LDS-transposed tiles.
// 1024 blocks, ~5 MB traffic (~2 us). Proven code.
// ---------------------------------------------------------------------------
__global__ __launch_bounds__(256)
void prep_b_kernel(const float* __restrict__ B, u8* __restrict__ Bt) {
    __shared__ float tile[32][33];
    const int tid = threadIdx.x;
    const int bid = (int)blockIdx.x;
    const int n0 = (bid & 31) * 32;
    const int k0 = (bid >> 5) * 32;
    const int tx = tid & 31;
    const int ty = tid >> 5;   // 0..7
#pragma unroll
    for (int i = 0; i < 32; i += 8)
        tile[ty + i][tx] = B[(size_t)(k0 + ty + i) * N_GLOB + n0 + tx];
    __syncthreads();
#pragma unroll
    for (int i = 0; i < 32; i += 8) {
        int w = __builtin_amdgcn_cvt_pk_fp8_f32(tile[tx][ty + i], 0.f, 0, false);
        Bt[(size_t)(n0 + ty + i) * K_GLOB + k0 + tx] = (u8)(w & 0xFF);
    }
}

// ---------------------------------------------------------------------------
// Fused GEMM: A f32 -> fp8 LDS panel (once), Bt fp8 streamed, f32 C out.
// ---------------------------------------------------------------------------
__global__ __launch_bounds__(256)
void gemm_fused_lds_kernel(const float* __restrict__ A,
                           const u8* __restrict__ Bt,
                           float* __restrict__ C)
{
    // A panel: 64 rows x 1024 fp8 = 64 KB @0 (swizzled 16B chunks).
    // B tiles: 2 buffers of [256 n-rows][128 B] = 32 KB @65536, @98304.
    __shared__ __attribute__((aligned(16))) char smem[131072];

    const int tid  = threadIdx.x;
    const int wave = tid >> 6;      // 0..3
    const int lane = tid & 63;
    const int wr   = wave >> 1;     // wave row: 32 rows each
    const int wc   = wave & 1;      // wave col: 128 cols each
    const int l32  = lane & 31;
    const int half = lane >> 5;     // k-half selector of the MFMA operand
    const int swz  = lane & 7;      // fragment row & 7 (rows == l32 mod 8)

    const int b   = (int)blockIdx.x;    // 0..255, one block per CU
    const int m0  = b * BM;
    const int ch0 = (b >> 3) & 3;       // per-block chunk rotation (L2 spread)

    // B staging map: issue covers 8 n-rows; lane L -> row (L>>3), LDS chunk
    // position p = L&7 holding global chunk c = p ^ (L>>3) (pre-swizzled src).
    const int srow = lane >> 3;
    const int sp   = lane & 7;
    const int sc   = sp ^ srow;

    const int scale1 = 0x7F7F7F7F;   // e8m0 127 = 2^0 in every byte
    const float LN2 = 0.69314718055994530942f;

    // Stage B tile for pipeline step v into buffer bufsel (8 gloads/thread).
#define STAGE(v, bufsel)                                                      \
    {                                                                         \
        const int chv = (((v) >> 3) + ch0) & 3;                               \
        const int ktv = (v) & 7;                                              \
        const u8* srcb = Bt + (size_t)(chv * BNC + srow) * K_GLOB             \
                            + ktv * 128 + sc * 16;                            \
        char* dstb = smem + 65536 + (bufsel) * 32768 + wave * 1024;           \
        _Pragma("unroll")                                                     \
        for (int s_ = 0; s_ < 8; ++s_)                                        \
            gload_lds16(srcb + (size_t)(s_ * 4 + wave) * 8 * K_GLOB,         \
                        dstb + s_ * 4096);                                    \
    }

    // ---- issue B tile 0 prefetch first (lands during the A phase)
    STAGE(0, 0);

    // ---- A phase: read 64x1024 f32 panel once, convert, store fp8 to LDS.
    // Pass p: thread handles chunk g = p*256+tid -> row p*4+wave, chunk tid&63.
    // Global reads perfectly coalesced (wave covers 4 KB contiguous / instr).
    {
        const int cpos = tid & 63;
#pragma unroll 4
        for (int p = 0; p < 16; ++p) {
            const int row = p * 4 + wave;
            const float* src = A + (size_t)(m0 + row) * K_GLOB + cpos * 16;
            f32x4 f0 = *(const f32x4*)(src);
            f32x4 f1 = *(const f32x4*)(src + 4);
            f32x4 f2 = *(const f32x4*)(src + 8);
            f32x4 f3 = *(const f32x4*)(src + 12);
            u32x4 o;
            o.x = cvt4_fp8(f0.x, f0.y, f0.z, f0.w);
            o.y = cvt4_fp8(f1.x, f1.y, f1.z, f1.w);
            o.z = cvt4_fp8(f2.x, f2.y, f2.z, f2.w);
            o.w = cvt4_fp8(f3.x, f3.y, f3.z, f3.w);
            const int pos = cpos ^ (row & 7);
            *(u32x4*)(smem + row * 1024 + pos * 16) = o;
        }
    }
    __syncthreads();   // drains vm (A loads + B tile0 DMA) and lgkm (A LDS)

    const char* aBase = smem + (size_t)(wr * 32 + l32) * 1024;

    for (int cc = 0; cc < NCH; ++cc) {
        const int ch  = (cc + ch0) & 3;
        const int n0c = ch * BNC;

        f32x16 acc[4];
#pragma unroll
        for (int j = 0; j < 4; ++j)
#pragma unroll
            for (int r = 0; r < 16; ++r)
                acc[j][r] = 0.f;

        for (int kt = 0; kt < NKT; ++kt) {
            const int v = cc * NKT + kt;
            // prefetch step v+1 into the other buffer; wait for step v's 8
            if (v + 1 < NT) {
                STAGE(v + 1, (v + 1) & 1);
                VMCNT(8);
            } else {
                VMCNT(0);
            }
            barrier_raw();   // all waves' tile-v DMA landed in LDS

            const char* bBase = smem + 65536 + (v & 1) * 32768;
#pragma unroll
            for (int s = 0; s < 2; ++s) {       // two MX K=64 steps
                const int c0l = s * 4 + half * 2;
                const int p0 = ((c0l    ) ^ swz) * 16;
                const int p1 = ((c0l + 1) ^ swz) * 16;
                i32x8 af;
                {
                    u32x4 lo = *(const u32x4*)(aBase + kt * 128 + p0);
                    u32x4 hi = *(const u32x4*)(aBase + kt * 128 + p1);
                    af[0] = lo.x; af[1] = lo.y; af[2] = lo.z; af[3] = lo.w;
                    af[4] = hi.x; af[5] = hi.y; af[6] = hi.z; af[7] = hi.w;
                }
                i32x8 bf[4];
#pragma unroll
                for (int j = 0; j < 4; ++j) {
                    const char* bRow = bBase + (size_t)(wc * 128 + j * 32 + l32) * 128;
                    u32x4 lo = *(const u32x4*)(bRow + p0);
                    u32x4 hi = *(const u32x4*)(bRow + p1);
                    bf[j][0] = lo.x; bf[j][1] = lo.y; bf[j][2] = lo.z; bf[j][3] = lo.w;
                    bf[j][4] = hi.x; bf[j][5] = hi.y; bf[j][6] = hi.z; bf[j][7] = hi.w;
                }
#pragma unroll
                for (int j = 0; j < 4; ++j)
                    acc[j] = __builtin_amdgcn_mfma_scale_f32_32x32x64_f8f6f4(
                        af, bf[j], acc[j],
                        0 /*cbsz: A=fp8 e4m3*/, 0 /*blgp: B=fp8 e4m3*/,
                        0, scale1, 0, scale1);
            }
            barrier_raw();   // reads done before buf(v&1) is overwritten
        }

        // ---- epilogue for this chunk: direct nontemporal dword stores.
        // 32x32 C/D layout: col=lane&31, row32=(r&3)+8*(r>>2)+4*half.
        // Lanes 0-31 and 32-63 of each store cover two full 128B lines.
        {
            const int rowBase = m0 + wr * 32 + 4 * half;
#pragma unroll
            for (int j = 0; j < 4; ++j) {
                const int col = n0c + wc * 128 + j * 32 + l32;
#pragma unroll
                for (int r = 0; r < 16; ++r) {
                    const int row = rowBase + (r & 3) + 8 * (r >> 2);
                    float vv = fmaxf(acc[j][r], 1.17549435e-38f);
                    __builtin_nontemporal_store(__log2f(vv) * LN2,
                        &C[(size_t)row * N_GLOB + col]);
                }
            }
        }
    }
#undef STAGE
}

// ---------------------------------------------------------------------------
// Fallback (round-1 kernel): fused fp32->bf16 staging, padded LDS.
// Used only if ws can't hold Bt (1 MiB).
// ---------------------------------------------------------------------------
#define FBM 128
#define FBN 128
#define LDK 40
__global__ __launch_bounds__(256)
void logmm_fused_kernel(const float* __restrict__ A,
                        const float* __restrict__ Bf,
                        float* __restrict__ C)
{
    __shared__ u16 As[FBM][LDK];
    __shared__ u16 Bs[FBN][LDK];

    const int tid  = threadIdx.x;
    const int lane = tid & 63;
    const int wave = tid >> 6;
    const int wr   = wave >> 1;
    const int wc   = wave & 1;
    const int quad = lane >> 4;
    const int l16  = lane & 15;

    const int m0 = blockIdx.y * FBM;
    const int n0 = blockIdx.x * FBN;

    f32x4 acc[4][4];
#pragma unroll
    for (int i = 0; i < 4; ++i)
#pragma unroll
        for (int j = 0; j < 4; ++j)
            acc[i][j] = f32x4{0.f, 0.f, 0.f, 0.f};

    const int ga_row = tid >> 2;
    const int ga_c8  = (tid & 3) * 8;
    const int fb_nt = tid >> 3;
    const int fb_kt = tid & 7;

    for (int kt = 0; kt < K_GLOB / 32; ++kt) {
        const int k0 = kt * 32;
#pragma unroll
        for (int s = 0; s < 2; ++s) {
            const int row = ga_row + s * 64;
            const float* src = A + (size_t)(m0 + row) * K_GLOB + k0 + ga_c8;
            f32x4 f0 = *(const f32x4*)src;
            f32x4 f1 = *(const f32x4*)(src + 4);
            u32x4 o;
            o.x = pack2_bf16(f0.x, f0.y);
            o.y = pack2_bf16(f0.z, f0.w);
            o.z = pack2_bf16(f1.x, f1.y);
            o.w = pack2_bf16(f1.z, f1.w);
            *(u32x4*)&As[row][ga_c8] = o;
        }
        {
            f32x4 r0 = *(const f32x4*)(Bf + (size_t)(k0 + fb_kt * 4 + 0) * N_GLOB + n0 + fb_nt * 4);
            f32x4 r1 = *(const f32x4*)(Bf + (size_t)(k0 + fb_kt * 4 + 1) * N_GLOB + n0 + fb_nt * 4);
            f32x4 r2 = *(const f32x4*)(Bf + (size_t)(k0 + fb_kt * 4 + 2) * N_GLOB + n0 + fb_nt * 4);
            f32x4 r3 = *(const f32x4*)(Bf + (size_t)(k0 + fb_kt * 4 + 3) * N_GLOB + n0 + fb_nt * 4);
#pragma unroll
            for (int j = 0; j < 4; ++j) {
                u32x2 o;
                o.x = pack2_bf16(r0[j], r1[j]);
                o.y = pack2_bf16(r2[j], r3[j]);
                *(u32x2*)&Bs[fb_nt * 4 + j][fb_kt * 4] = o;
            }
        }

        __syncthreads();

        bf16x8 af[4], bfr[4];
#pragma unroll
        for (int i = 0; i < 4; ++i)
            af[i] = __builtin_bit_cast(bf16x8, *(const u32x4*)&As[wr * 64 + i * 16 + l16][quad * 8]);
#pragma unroll
        for (int j = 0; j < 4; ++j)
            bfr[j] = __builtin_bit_cast(bf16x8, *(const u32x4*)&Bs[wc * 64 + j * 16 + l16][quad * 8]);

#pragma unroll
        for (int i = 0; i < 4; ++i)
#pragma unroll
            for (int j = 0; j < 4; ++j)
                acc[i][j] = __builtin_amdgcn_mfma_f32_16x16x32_bf16(af[i], bfr[j], acc[i][j], 0, 0, 0);

        __syncthreads();
    }

    const float LN2 = 0.69314718055994530942f;
#pragma unroll
    for (int i = 0; i < 4; ++i) {
#pragma unroll
        for (int j = 0; j < 4; ++j) {
            const int col = n0 + wc * 64 + j * 16 + l16;
#pragma unroll
            for (int r = 0; r < 4; ++r) {
                const int row = m0 + wr * 64 + i * 16 + quad * 4 + r;
                float v = fmaxf(acc[i][j][r], 1.17549435e-38f);
                C[(size_t)row * N_GLOB + col] = __log2f(v) * LN2;
            }
        }
    }
}

extern "C" void kernel_launch(void* const* d_in, const int* in_sizes, int n_in,
                              void* d_out, int out_size, void* d_ws, size_t ws_size,
                              hipStream_t stream) {
    const float* A = (const float*)d_in[0];   // x: [16384,1024]
    const float* B = (const float*)d_in[1];   // matrix: [1024,1024]
    float* C = (float*)d_out;

    const size_t bt_bytes = (size_t)N_GLOB * K_GLOB;        // 1 MiB fp8

    if (ws_size >= bt_bytes) {
        u8* Bt = (u8*)d_ws;
        prep_b_kernel<<<1024, 256, 0, stream>>>(B, Bt);
        gemm_fused_lds_kernel<<<M_GLOB / BM, 256, 0, stream>>>(A, Bt, C);
    } else {
        logmm_fused_kernel<<<dim3(N_GLOB / FBN, M_GLOB / FBM), 256, 0, stream>>>(A, B, C);
    }
}